// Round 10
// baseline (236.118 us; speedup 1.0000x reference)
//
#include <hip/hip_runtime.h>

// DoReFa dense: out = q_in(3-bit) @ (sign(W)*E) + b,  E = mean|W|
//   out[i,j] = (E/7) * sum_k r[i,k]*sign(W[k,j]),  r in 0..7 -- exact in i8 MFMA.
// R10: cross-block overlap via occupancy. 128x128 tile, 4 waves, 3x16KB LDS
//      buffers -> 3 blocks/CU (3 waves/SIMD): independent blocks drift so one
//      block's ds_read burst overlaps another's MFMA burst (m114 mechanism).
//      R4-verified drift body (1 barrier/tile, vmcnt(4), 3-buffer rotation,
//      A64||B64 line + 8-slot XOR swizzle). k_scale fused into k_quant_a.

static constexpr int BATCH  = 8192;
static constexpr int IN_CH  = 4096;
static constexpr int NUNITS = 4096;
static constexpr int TPB    = 256;

typedef int v4i __attribute__((ext_vector_type(4)));

// ---- workspace layout ----
static constexpr size_t A8_OFF   = 0;
static constexpr size_t A8_BYTES = (size_t)BATCH * IN_CH;    // 32 MB
static constexpr size_t BT_OFF   = A8_OFF + A8_BYTES;
static constexpr size_t BT_BYTES = (size_t)NUNITS * IN_CH;   // 16 MB
static constexpr int    NPART    = 4096;
static constexpr size_t PART_OFF = BT_OFF + BT_BYTES;
static constexpr size_t SCALE_OFF= PART_OFF + NPART * sizeof(float);

// -------------------------- sign(W) transpose to [N][K]  +  fused |W| partial sum
__global__ __launch_bounds__(TPB) void k_signT(const float* __restrict__ W,
                                               char* __restrict__ bt,
                                               float* __restrict__ partials) {
    __shared__ char tile[64][68];
    __shared__ float red[TPB];
    const int bk = blockIdx.x & 63;
    const int bn = blockIdx.x >> 6;
    const int t  = threadIdx.x;
    const int c  = t & 63;
    const int r0 = t >> 6;
    float asum = 0.f;
#pragma unroll
    for (int i = 0; i < 16; ++i) {
        int r = i * 4 + r0;
        float w = W[(size_t)(bk * 64 + r) * NUNITS + bn * 64 + c];
        asum += fabsf(w);
        tile[c][r] = (w > 0.f) ? 1 : ((w < 0.f) ? -1 : 0);
    }
    __syncthreads();
    const int n  = t >> 2;
    const int kk = (t & 3) * 16;
    char o[16];
#pragma unroll
    for (int j = 0; j < 16; ++j) o[j] = tile[n][kk + j];
    *(uint4*)(bt + (size_t)(bn * 64 + n) * IN_CH + bk * 64 + kk) = *(const uint4*)o;

    red[t] = asum;
    __syncthreads();
    for (int off = TPB / 2; off > 0; off >>= 1) {
        if (t < off) red[t] += red[t + off];
        __syncthreads();
    }
    if (t == 0) partials[blockIdx.x] = red[0];
}

// ------------------------------------------------------------- quantize A (+ fused scale)
__device__ __forceinline__ unsigned int q4(float4 v) {
    unsigned int b0 = (unsigned int)(int)rintf(fminf(1.0f, fabsf(v.x)) * 7.0f);
    unsigned int b1 = (unsigned int)(int)rintf(fminf(1.0f, fabsf(v.y)) * 7.0f);
    unsigned int b2 = (unsigned int)(int)rintf(fminf(1.0f, fabsf(v.z)) * 7.0f);
    unsigned int b3 = (unsigned int)(int)rintf(fminf(1.0f, fabsf(v.w)) * 7.0f);
    return b0 | (b1 << 8) | (b2 << 16) | (b3 << 24);
}

__global__ __launch_bounds__(TPB) void k_quant_a(const float4* __restrict__ x4,
                                                 uint4* __restrict__ a16,
                                                 const float* __restrict__ partials,
                                                 float* __restrict__ scale) {
    if (blockIdx.x == 0) {   // fused scale finalize (partials ready: same stream)
        __shared__ float red[TPB];
        float s = 0.f;
        for (int i = threadIdx.x; i < NPART; i += TPB) s += partials[i];
        red[threadIdx.x] = s;
        __syncthreads();
        for (int off = TPB / 2; off > 0; off >>= 1) {
            if ((int)threadIdx.x < off) red[threadIdx.x] += red[threadIdx.x + off];
            __syncthreads();
        }
        if (threadIdx.x == 0) {
            float E = red[0] / (float)((size_t)IN_CH * NUNITS);
            *scale = E / 7.0f;
        }
    }
    const size_t t = (size_t)blockIdx.x * TPB + threadIdx.x;
    uint4 o;
    o.x = q4(x4[t * 4 + 0]);
    o.y = q4(x4[t * 4 + 1]);
    o.z = q4(x4[t * 4 + 2]);
    o.w = q4(x4[t * 4 + 3]);
    a16[t] = o;
}

// ---------------------------------------------------------------- GEMM
// 128x128 block tile, BK=64, 4 waves (2x2, wave tile 64x64), mfma_i32_16x16x64_i8.
// LDS: 3 buffers x [128 lines][128B]; line L = A-row L (64B) || B-row L (64B);
// 16B slot swizzle: phys = logical ^ (L&7).  3 blocks/CU.
__device__ __forceinline__ void gload_lds16(const void* g, void* l) {
    __builtin_amdgcn_global_load_lds((const __attribute__((address_space(1))) void*)g,
                                     (__attribute__((address_space(3))) void*)l,
                                     16, 0, 0);
}

#define VMCNT4   asm volatile("s_waitcnt vmcnt(4)" ::: "memory")
#define VMCNT0   asm volatile("s_waitcnt vmcnt(0)" ::: "memory")
#define LGKM0    asm volatile("s_waitcnt lgkmcnt(0)" ::: "memory")
#define SCHEDB   __builtin_amdgcn_sched_barrier(0)
#define BARRIER  __builtin_amdgcn_s_barrier()
#define PRIO1    __builtin_amdgcn_s_setprio(1)
#define PRIO0    __builtin_amdgcn_s_setprio(0)

static constexpr int NT = IN_CH / 64;   // 64 K-tiles

__global__ __launch_bounds__(256, 3) void k_gemm(const char* __restrict__ A8,
                                                 const char* __restrict__ BT,
                                                 const float* __restrict__ scale_p,
                                                 const float* __restrict__ bias,
                                                 float* __restrict__ out) {
    __shared__ char Ms[3][16384];   // 48 KiB -> 3 blocks/CU

    const int t    = threadIdx.x;
    const int bid  = blockIdx.x;                    // 2048 blocks
    const int swzb = (bid & 7) * 256 + (bid >> 3);  // XCD swizzle (bijective: 2048%8==0)
    const int bRow = swzb >> 5;                     // 0..63
    const int bCol = swzb & 31;                     // 0..31
    const int lane = t & 63;
    const int wid  = t >> 6;
    const int wr   = wid >> 1;                      // 0..1
    const int wc   = wid & 1;                       // 0..1
    const int lr   = lane & 15;
    const int lk4  = lane >> 4;                     // 0..3

    // frag read byte offsets within a 128B line (phys slot = logical ^ (L&7); L&7 == lr&7)
    const int aoff = ((lk4 ^ (lr & 7)) << 4);       // A logical slots 0..3
    const int boff = aoff ^ 64;                     // B logical slots 4..7

    // stage addressing: issue h covers line h*32 + (t>>3), phys slot t&7
    const int lslot = (t & 7) ^ ((t >> 3) & 7);     // logical slot at this dest
    const char* mbase = (lslot < 4)
        ? (A8 + (size_t)(bRow * 128) * IN_CH)
        : (BT + (size_t)(bCol * 128) * IN_CH);
    const char* sbase = mbase + (size_t)(t >> 3) * IN_CH + ((lslot & 3) << 4);

    v4i acc[4][4] = {};

#define STAGE4(kt, STG)                                                          \
    _Pragma("unroll") for (int h = 0; h < 4; ++h)                                \
        gload_lds16(sbase + (size_t)h * 32 * IN_CH + (size_t)(kt) * 64,          \
                    (STG) + h * 4096 + t * 16)

#define TILE(kt, CUR, STG, LAST)                                                 \
    do {                                                                         \
        SCHEDB; LGKM0;                                                           \
        if (LAST) { VMCNT0; } else { VMCNT4; }                                   \
        BARRIER; SCHEDB;                                                         \
        if ((kt) + 2 < NT) { STAGE4((kt) + 2, STG); }                            \
        v4i a_[4], b_[4];                                                        \
        _Pragma("unroll") for (int m = 0; m < 4; ++m)                            \
            a_[m] = *(const v4i*)((CUR) + (wr * 64 + m * 16 + lr) * 128 + aoff); \
        _Pragma("unroll") for (int n = 0; n < 4; ++n)                            \
            b_[n] = *(const v4i*)((CUR) + (wc * 64 + n * 16 + lr) * 128 + boff); \
        PRIO1;                                                                   \
        _Pragma("unroll") for (int m = 0; m < 4; ++m)                            \
            _Pragma("unroll") for (int n = 0; n < 4; ++n)                        \
                acc[m][n] = __builtin_amdgcn_mfma_i32_16x16x64_i8(               \
                    a_[m], b_[n], acc[m][n], 0, 0, 0);                           \
        PRIO0;                                                                   \
    } while (0)

    char* B0 = (char*)Ms[0];
    char* B1 = (char*)Ms[1];
    char* B2 = (char*)Ms[2];

    // prologue: stage tiles 0 and 1 (8 issues outstanding)
    STAGE4(0, B0);
    STAGE4(1, B1);

    // tiles 0..62 (21 x 3, static rotation), tail tile 63
    for (int T = 0; T < NT - 1; T += 3) {
        TILE(T,     B0, B2, false);
        TILE(T + 1, B1, B0, false);
        TILE(T + 2, B2, B1, false);
    }
    TILE(NT - 1, B0, B2, true);

    // ---- epilogue
    const float scale = *scale_p;
    const int orow0 = bRow * 128 + wr * 64;
    const int ocol0 = bCol * 128 + wc * 64;
#pragma unroll
    for (int m = 0; m < 4; ++m) {
#pragma unroll
        for (int n = 0; n < 4; ++n) {
            const int col = ocol0 + n * 16 + lr;
            const float bb = bias[col];
            const int rbase = orow0 + m * 16 + lk4 * 4;
#pragma unroll
            for (int j = 0; j < 4; ++j)
                out[(size_t)(rbase + j) * NUNITS + col] = scale * (float)acc[m][n][j] + bb;
        }
    }
#undef STAGE4
#undef TILE
}

// ---------------------------------------------------------------- launch
extern "C" void kernel_launch(void* const* d_in, const int* in_sizes, int n_in,
                              void* d_out, int out_size, void* d_ws, size_t ws_size,
                              hipStream_t stream) {
    const float* x  = (const float*)d_in[0];
    const float* W  = (const float*)d_in[1];
    const float* b  = (const float*)d_in[2];
    float* out      = (float*)d_out;

    char*  ws       = (char*)d_ws;
    char*  A8       = ws + A8_OFF;
    char*  BT       = ws + BT_OFF;
    float* partials = (float*)(ws + PART_OFF);
    float* scale    = (float*)(ws + SCALE_OFF);

    k_signT<<<(IN_CH / 64) * (NUNITS / 64), TPB, 0, stream>>>(W, BT, partials);
    k_quant_a<<<(BATCH * (IN_CH / 16)) / TPB, TPB, 0, stream>>>((const float4*)x, (uint4*)A8,
                                                                partials, scale);
    k_gemm<<<(BATCH / 128) * (NUNITS / 128), TPB, 0, stream>>>(A8, BT, scale, b, out);
}

// Round 11
// 173.436 us; speedup vs baseline: 1.3614x; 1.3614x over previous
//
#include <hip/hip_runtime.h>

// DoReFa dense: out = q_in(3-bit) @ (sign(W)*E) + b,  E = mean|W|
//   out[i,j] = (E/7) * sum_k r[i,k]*sign(W[k,j]),  r in 0..7 -- exact in i8 MFMA.
// R11: 256x256 tile, 16 waves (4x4, wave-tile 64x64, acc=64 VGPR -> 4 waves/SIMD),
//      8 ds_reads/wave/tile => staggered read completion overlaps DS with MFMA
//      across waves. R4-verified drift body: 3x32KB buffers, 1 barrier/tile,
//      vmcnt(2) gate, A64||B64 lines + 8-slot XOR swizzle, setprio. 256-tile
//      keeps FETCH at 147MB (R10's 128-tile blew it to 533MB).

static constexpr int BATCH  = 8192;
static constexpr int IN_CH  = 4096;
static constexpr int NUNITS = 4096;
static constexpr int TPB    = 256;

typedef int v4i __attribute__((ext_vector_type(4)));

// ---- workspace layout ----
static constexpr size_t A8_OFF   = 0;
static constexpr size_t A8_BYTES = (size_t)BATCH * IN_CH;    // 32 MB
static constexpr size_t BT_OFF   = A8_OFF + A8_BYTES;
static constexpr size_t BT_BYTES = (size_t)NUNITS * IN_CH;   // 16 MB
static constexpr int    NPART    = 4096;
static constexpr size_t PART_OFF = BT_OFF + BT_BYTES;
static constexpr size_t SCALE_OFF= PART_OFF + NPART * sizeof(float);

// -------------------------- sign(W) transpose to [N][K]  +  fused |W| partial sum
__global__ __launch_bounds__(TPB) void k_signT(const float* __restrict__ W,
                                               char* __restrict__ bt,
                                               float* __restrict__ partials) {
    __shared__ char tile[64][68];
    __shared__ float red[TPB];
    const int bk = blockIdx.x & 63;
    const int bn = blockIdx.x >> 6;
    const int t  = threadIdx.x;
    const int c  = t & 63;
    const int r0 = t >> 6;
    float asum = 0.f;
#pragma unroll
    for (int i = 0; i < 16; ++i) {
        int r = i * 4 + r0;
        float w = W[(size_t)(bk * 64 + r) * NUNITS + bn * 64 + c];
        asum += fabsf(w);
        tile[c][r] = (w > 0.f) ? 1 : ((w < 0.f) ? -1 : 0);
    }
    __syncthreads();
    const int n  = t >> 2;
    const int kk = (t & 3) * 16;
    char o[16];
#pragma unroll
    for (int j = 0; j < 16; ++j) o[j] = tile[n][kk + j];
    *(uint4*)(bt + (size_t)(bn * 64 + n) * IN_CH + bk * 64 + kk) = *(const uint4*)o;

    red[t] = asum;
    __syncthreads();
    for (int off = TPB / 2; off > 0; off >>= 1) {
        if (t < off) red[t] += red[t + off];
        __syncthreads();
    }
    if (t == 0) partials[blockIdx.x] = red[0];
}

// ------------------------------------------------------------- quantize A (+ fused scale)
__device__ __forceinline__ unsigned int q4(float4 v) {
    unsigned int b0 = (unsigned int)(int)rintf(fminf(1.0f, fabsf(v.x)) * 7.0f);
    unsigned int b1 = (unsigned int)(int)rintf(fminf(1.0f, fabsf(v.y)) * 7.0f);
    unsigned int b2 = (unsigned int)(int)rintf(fminf(1.0f, fabsf(v.z)) * 7.0f);
    unsigned int b3 = (unsigned int)(int)rintf(fminf(1.0f, fabsf(v.w)) * 7.0f);
    return b0 | (b1 << 8) | (b2 << 16) | (b3 << 24);
}

__global__ __launch_bounds__(TPB) void k_quant_a(const float4* __restrict__ x4,
                                                 uint4* __restrict__ a16,
                                                 const float* __restrict__ partials,
                                                 float* __restrict__ scale) {
    if (blockIdx.x == 0) {
        __shared__ float red[TPB];
        float s = 0.f;
        for (int i = threadIdx.x; i < NPART; i += TPB) s += partials[i];
        red[threadIdx.x] = s;
        __syncthreads();
        for (int off = TPB / 2; off > 0; off >>= 1) {
            if ((int)threadIdx.x < off) red[threadIdx.x] += red[threadIdx.x + off];
            __syncthreads();
        }
        if (threadIdx.x == 0) {
            float E = red[0] / (float)((size_t)IN_CH * NUNITS);
            *scale = E / 7.0f;
        }
    }
    const size_t t = (size_t)blockIdx.x * TPB + threadIdx.x;
    uint4 o;
    o.x = q4(x4[t * 4 + 0]);
    o.y = q4(x4[t * 4 + 1]);
    o.z = q4(x4[t * 4 + 2]);
    o.w = q4(x4[t * 4 + 3]);
    a16[t] = o;
}

// ---------------------------------------------------------------- GEMM
// 256x256 block tile, BK=64, 16 waves (4x4, wave tile 64x64), mfma_i32_16x16x64_i8.
// LDS: 3 buffers x [256 lines][128B]; line L = A-row L (64B) || B-row L (64B);
// 16B slot swizzle: phys = logical ^ (L&7).
__device__ __forceinline__ void gload_lds16(const void* g, void* l) {
    __builtin_amdgcn_global_load_lds((const __attribute__((address_space(1))) void*)g,
                                     (__attribute__((address_space(3))) void*)l,
                                     16, 0, 0);
}

#define VMCNT2   asm volatile("s_waitcnt vmcnt(2)" ::: "memory")
#define VMCNT0   asm volatile("s_waitcnt vmcnt(0)" ::: "memory")
#define LGKM0    asm volatile("s_waitcnt lgkmcnt(0)" ::: "memory")
#define SCHEDB   __builtin_amdgcn_sched_barrier(0)
#define BARRIER  __builtin_amdgcn_s_barrier()
#define PRIO1    __builtin_amdgcn_s_setprio(1)
#define PRIO0    __builtin_amdgcn_s_setprio(0)

static constexpr int NT = IN_CH / 64;   // 64 K-tiles

__global__ __launch_bounds__(1024, 4) void k_gemm(const char* __restrict__ A8,
                                                  const char* __restrict__ BT,
                                                  const float* __restrict__ scale_p,
                                                  const float* __restrict__ bias,
                                                  float* __restrict__ out) {
    __shared__ char Ms[3][32768];   // 96 KiB

    const int t    = threadIdx.x;                 // 0..1023
    const int bid  = blockIdx.x;                  // 512 blocks
    const int swzb = (bid & 7) * 64 + (bid >> 3); // XCD swizzle (bijective: 512%8==0)
    const int bRow = swzb >> 4;                   // 0..31
    const int bCol = swzb & 15;                   // 0..15
    const int lane = t & 63;
    const int wid  = t >> 6;                      // 0..15
    const int wr   = wid >> 2;                    // 0..3
    const int wc   = wid & 3;                     // 0..3
    const int lr   = lane & 15;
    const int lk4  = lane >> 4;                   // 0..3

    // frag read offsets within a 128B line (phys slot = logical ^ (L&7); L&7 == lr&7)
    const int aoff = ((lk4 ^ (lr & 7)) << 4);     // A logical slots 0..3
    const int boff = aoff ^ 64;                   // B logical slots 4..7

    // staging: issue h covers line h*128 + (t>>3), phys slot t&7
    const int lslot = (t & 7) ^ ((t >> 3) & 7);
    const char* mbase = (lslot < 4)
        ? (A8 + (size_t)(bRow * 256) * IN_CH)
        : (BT + (size_t)(bCol * 256) * IN_CH);
    const char* sbase = mbase + (size_t)(t >> 3) * IN_CH + ((lslot & 3) << 4);

    v4i acc[4][4] = {};

#define STAGE2(kt, STG)                                                          \
    _Pragma("unroll") for (int h = 0; h < 2; ++h)                                \
        gload_lds16(sbase + (size_t)h * 128 * IN_CH + (size_t)(kt) * 64,         \
                    (STG) + h * 16384 + t * 16)

#define TILE(kt, CUR, STG, LAST)                                                 \
    do {                                                                         \
        SCHEDB; LGKM0;                                                           \
        if (LAST) { VMCNT0; } else { VMCNT2; }                                   \
        BARRIER; SCHEDB;                                                         \
        if ((kt) + 2 < NT) { STAGE2((kt) + 2, STG); }                            \
        v4i a_[4], b_[4];                                                        \
        _Pragma("unroll") for (int m = 0; m < 4; ++m)                            \
            a_[m] = *(const v4i*)((CUR) + (wr * 64 + m * 16 + lr) * 128 + aoff); \
        _Pragma("unroll") for (int n = 0; n < 4; ++n)                            \
            b_[n] = *(const v4i*)((CUR) + (wc * 64 + n * 16 + lr) * 128 + boff); \
        PRIO1;                                                                   \
        _Pragma("unroll") for (int m = 0; m < 4; ++m)                            \
            _Pragma("unroll") for (int n = 0; n < 4; ++n)                        \
                acc[m][n] = __builtin_amdgcn_mfma_i32_16x16x64_i8(               \
                    a_[m], b_[n], acc[m][n], 0, 0, 0);                           \
        PRIO0;                                                                   \
    } while (0)

    char* B0 = (char*)Ms[0];
    char* B1 = (char*)Ms[1];
    char* B2 = (char*)Ms[2];

    // prologue: stage tiles 0 and 1 (4 issues outstanding)
    STAGE2(0, B0);
    STAGE2(1, B1);

    // tiles 0..62 (21 x 3 rotation), tail tile 63
    for (int T = 0; T < NT - 1; T += 3) {
        TILE(T,     B0, B2, false);
        TILE(T + 1, B1, B0, false);
        TILE(T + 2, B2, B1, false);
    }
    TILE(NT - 1, B0, B2, true);

    // ---- epilogue
    const float scale = *scale_p;
    const int orow0 = bRow * 256 + wr * 64;
    const int ocol0 = bCol * 256 + wc * 64;
#pragma unroll
    for (int m = 0; m < 4; ++m) {
#pragma unroll
        for (int n = 0; n < 4; ++n) {
            const int col = ocol0 + n * 16 + lr;
            const float bb = bias[col];
            const int rbase = orow0 + m * 16 + lk4 * 4;
#pragma unroll
            for (int j = 0; j < 4; ++j)
                out[(size_t)(rbase + j) * NUNITS + col] = scale * (float)acc[m][n][j] + bb;
        }
    }
#undef STAGE2
#undef TILE
}

// ---------------------------------------------------------------- launch
extern "C" void kernel_launch(void* const* d_in, const int* in_sizes, int n_in,
                              void* d_out, int out_size, void* d_ws, size_t ws_size,
                              hipStream_t stream) {
    const float* x  = (const float*)d_in[0];
    const float* W  = (const float*)d_in[1];
    const float* b  = (const float*)d_in[2];
    float* out      = (float*)d_out;

    char*  ws       = (char*)d_ws;
    char*  A8       = ws + A8_OFF;
    char*  BT       = ws + BT_OFF;
    float* partials = (float*)(ws + PART_OFF);
    float* scale    = (float*)(ws + SCALE_OFF);

    k_signT<<<(IN_CH / 64) * (NUNITS / 64), TPB, 0, stream>>>(W, BT, partials);
    k_quant_a<<<(BATCH * (IN_CH / 16)) / TPB, TPB, 0, stream>>>((const float4*)x, (uint4*)A8,
                                                                partials, scale);
    k_gemm<<<(BATCH / 256) * (NUNITS / 256), 1024, 0, stream>>>(A8, BT, scale, b, out);
}